// Round 2
// baseline (83.539 us; speedup 1.0000x reference)
//
#include <hip/hip_runtime.h>

#define NR 65536
#define RPB 4   // rays per 256-thread block (one wave per ray)

__global__ __launch_bounds__(256) void ray_sampler_kernel(
    const float* __restrict__ origins,
    const float* __restrict__ directions,
    const float* __restrict__ nearv,
    const float* __restrict__ farv,
    const float* __restrict__ weights,
    float* __restrict__ out)
{
    __shared__ float s_cdf[RPB][64];     // entries 0..62 used
    __shared__ float s_coarse[RPB][64];
    __shared__ float s_fine[RPB][128];
    __shared__ float s_z[RPB][192];

    const int tid  = threadIdx.x;
    const int wv   = tid >> 6;
    const int lane = tid & 63;
    const int r    = blockIdx.x * RPB + wv;

    const float nr  = nearv[r];
    const float fr  = farv[r];
    const float dnf = fr - nr;

    float dx = directions[3*r+0];
    float dy = directions[3*r+1];
    float dz = directions[3*r+2];
    const float invn = 1.0f / sqrtf(dx*dx + dy*dy + dz*dz);
    dx *= invn; dy *= invn; dz *= invn;
    const float ox = origins[3*r+0];
    const float oy = origins[3*r+1];
    const float oz = origins[3*r+2];

    // ---- CDF from 62 interior weights (weights[:,1:-1]) via wave prefix scan ----
    float w = 0.0f;
    if (lane < 62) w = weights[(size_t)r*64 + lane + 1] + 1e-5f;
    float sc = w;
    #pragma unroll
    for (int off = 1; off < 64; off <<= 1) {
        float t = __shfl_up(sc, off, 64);
        if (lane >= off) sc += t;
    }
    const float total = __shfl(sc, 63, 64);
    const float invT  = 1.0f / total;
    if (lane < 62) s_cdf[wv][lane + 1] = sc * invT;
    if (lane == 62) s_cdf[wv][0] = 0.0f;

    // coarse depths: linspace(near, far, 64)
    s_coarse[wv][lane] = nr + dnf * ((float)lane * (1.0f/63.0f));
    __syncthreads();

    // ---- 128 fine samples by inverse-CDF (searchsorted side='right') ----
    const float* cdf = s_cdf[wv];
    #pragma unroll
    for (int sIt = 0; sIt < 2; ++sIt) {
        const int s = lane + sIt * 64;
        const float u = (float)s * (1.0f/127.0f);
        int lo = 0, hi = 63;                 // answer in [0,63]: 6 iters (63->31->15->7->3->1->0)
        #pragma unroll
        for (int it = 0; it < 6; ++it) {
            if (lo < hi) {
                int mid = (lo + hi) >> 1;
                if (cdf[mid] <= u) lo = mid + 1; else hi = mid;
            }
        }
        int below = lo - 1; below = below < 0 ? 0 : (below > 62 ? 62 : below);
        int above = lo > 62 ? 62 : lo;
        const float cb = cdf[below], ca = cdf[above];
        // bins = midpoints: near + dnf*(j+0.5)/63
        const float bb = nr + dnf * (((float)below + 0.5f) * (1.0f/63.0f));
        const float ba = nr + dnf * (((float)above + 0.5f) * (1.0f/63.0f));
        float den = ca - cb;
        if (den < 1e-5f) den = 1.0f;
        const float tt = (u - cb) / den;
        s_fine[wv][s] = bb + tt * (ba - bb);
    }
    __syncthreads();

    // ---- merge coarse(64, sorted) + fine(128, sorted) -> z(192) sorted ----
    const float* fine   = s_fine[wv];
    const float* coarse = s_coarse[wv];
    {
        const float v = coarse[lane];
        int lo = 0, hi = 128;                // count fine < v: answer space [0,128] -> 8 iters
        #pragma unroll
        for (int it = 0; it < 8; ++it) {
            if (lo < hi) {
                int mid = (lo + hi) >> 1;
                if (fine[mid] < v) lo = mid + 1; else hi = mid;
            }
        }
        s_z[wv][lane + lo] = v;
    }
    #pragma unroll
    for (int sIt = 0; sIt < 2; ++sIt) {
        const int s = lane + sIt * 64;
        const float v = fine[s];
        int lo = 0, hi = 64;                 // count coarse <= v: answer space [0,64] -> 7 iters
        #pragma unroll
        for (int it = 0; it < 7; ++it) {
            if (lo < hi) {
                int mid = (lo + hi) >> 1;
                if (coarse[mid] <= v) lo = mid + 1; else hi = mid;
            }
        }
        s_z[wv][s + lo] = v;
    }
    __syncthreads();

    // ---- outputs: positions[N,192,3], viewdirs[N,192,3], z[N,192], deltas[N,192] ----
    const float* zm = s_z[wv];
    float4* pos4 = reinterpret_cast<float4*>(out) + (size_t)r * 144;
    float4* vd4  = reinterpret_cast<float4*>(out + (size_t)NR * 576)  + (size_t)r * 144;
    float4* z4   = reinterpret_cast<float4*>(out + (size_t)NR * 1152) + (size_t)r * 48;
    float4* dl4  = reinterpret_cast<float4*>(out + (size_t)NR * 1344) + (size_t)r * 48;

    #pragma unroll
    for (int qi = 0; qi < 3; ++qi) {
        const int q = lane + qi * 64;
        if (q < 144) {
            const int f = 4 * q;
            float4 p, v;
            #pragma unroll
            for (int m = 0; m < 4; ++m) {
                const int k = (f + m) / 3;
                const int c = (f + m) % 3;
                const float zz = zm[k];
                const float dc = (c == 0) ? dx : ((c == 1) ? dy : dz);
                const float oc = (c == 0) ? ox : ((c == 1) ? oy : oz);
                (&p.x)[m] = oc + zz * dc;
                (&v.x)[m] = dc;
            }
            pos4[q] = p;
            vd4[q]  = v;
        }
    }
    if (lane < 48) {
        const int f = 4 * lane;
        const float z0 = zm[f], z1 = zm[f+1], z2 = zm[f+2], z3 = zm[f+3];
        z4[lane] = make_float4(z0, z1, z2, z3);
        const bool hasNext = (f + 4) < 192;
        const float e3 = hasNext ? (zm[f+4] - z3) : (z3 - z2);
        dl4[lane] = make_float4(z1 - z0, z2 - z1, z3 - z2, e3);
    }
}

extern "C" void kernel_launch(void* const* d_in, const int* in_sizes, int n_in,
                              void* d_out, int out_size, void* d_ws, size_t ws_size,
                              hipStream_t stream) {
    const float* origins    = (const float*)d_in[0];
    const float* directions = (const float*)d_in[1];
    const float* nearv      = (const float*)d_in[2];
    const float* farv       = (const float*)d_in[3];
    const float* weights    = (const float*)d_in[4];
    float* out = (float*)d_out;

    dim3 grid(NR / RPB);
    dim3 block(256);
    ray_sampler_kernel<<<grid, block, 0, stream>>>(origins, directions, nearv, farv, weights, out);
}

// Round 4
// 82.763 us; speedup vs baseline: 1.0094x; 1.0094x over previous
//
#include <hip/hip_runtime.h>

#define NR 65536
#define RPB 4   // rays per 256-thread block (one wave per ray)

typedef float f32x4 __attribute__((ext_vector_type(4)));

__global__ __launch_bounds__(256) void ray_sampler_kernel(
    const float* __restrict__ origins,
    const float* __restrict__ directions,
    const float* __restrict__ nearv,
    const float* __restrict__ farv,
    const float* __restrict__ weights,
    float* __restrict__ out)
{
    __shared__ float s_cdf[RPB][64];     // entries 0..62 used
    __shared__ float s_coarse[RPB][64];
    __shared__ float s_fine[RPB][128];
    __shared__ float s_z[RPB][192];

    const int tid  = threadIdx.x;
    const int wv   = tid >> 6;
    const int lane = tid & 63;
    const int r    = blockIdx.x * RPB + wv;

    const float nr  = nearv[r];
    const float fr  = farv[r];
    const float dnf = fr - nr;

    float dx = directions[3*r+0];
    float dy = directions[3*r+1];
    float dz = directions[3*r+2];
    const float invn = 1.0f / sqrtf(dx*dx + dy*dy + dz*dz);
    dx *= invn; dy *= invn; dz *= invn;
    const float ox = origins[3*r+0];
    const float oy = origins[3*r+1];
    const float oz = origins[3*r+2];

    // ---- CDF from 62 interior weights (weights[:,1:-1]) via wave prefix scan ----
    float w = 0.0f;
    if (lane < 62) w = weights[(size_t)r*64 + lane + 1] + 1e-5f;
    float sc = w;
    #pragma unroll
    for (int off = 1; off < 64; off <<= 1) {
        float t = __shfl_up(sc, off, 64);
        if (lane >= off) sc += t;
    }
    const float total = __shfl(sc, 63, 64);
    const float invT  = 1.0f / total;
    if (lane < 62) s_cdf[wv][lane + 1] = sc * invT;
    if (lane == 62) s_cdf[wv][0] = 0.0f;

    // coarse depths: linspace(near, far, 64)
    s_coarse[wv][lane] = nr + dnf * ((float)lane * (1.0f/63.0f));
    __syncthreads();

    // ---- 128 fine samples by inverse-CDF (searchsorted side='right') ----
    const float* cdf = s_cdf[wv];
    #pragma unroll
    for (int sIt = 0; sIt < 2; ++sIt) {
        const int s = lane + sIt * 64;
        const float u = (float)s * (1.0f/127.0f);
        int lo = 0, hi = 63;                 // answer in [0,63]: 6 iters
        #pragma unroll
        for (int it = 0; it < 6; ++it) {
            if (lo < hi) {
                int mid = (lo + hi) >> 1;
                if (cdf[mid] <= u) lo = mid + 1; else hi = mid;
            }
        }
        int below = lo - 1; below = below < 0 ? 0 : (below > 62 ? 62 : below);
        int above = lo > 62 ? 62 : lo;
        const float cb = cdf[below], ca = cdf[above];
        // bins = midpoints: near + dnf*(j+0.5)/63
        const float bb = nr + dnf * (((float)below + 0.5f) * (1.0f/63.0f));
        const float ba = nr + dnf * (((float)above + 0.5f) * (1.0f/63.0f));
        float den = ca - cb;
        if (den < 1e-5f) den = 1.0f;
        const float tt = (u - cb) / den;
        s_fine[wv][s] = bb + tt * (ba - bb);
    }
    __syncthreads();

    // ---- merge coarse(64, sorted) + fine(128, sorted) -> z(192) sorted ----
    const float* fine   = s_fine[wv];
    const float* coarse = s_coarse[wv];
    {
        const float v = coarse[lane];
        int lo = 0, hi = 128;                // count fine < v: answer space [0,128] -> 8 iters
        #pragma unroll
        for (int it = 0; it < 8; ++it) {
            if (lo < hi) {
                int mid = (lo + hi) >> 1;
                if (fine[mid] < v) lo = mid + 1; else hi = mid;
            }
        }
        s_z[wv][lane + lo] = v;
    }
    #pragma unroll
    for (int sIt = 0; sIt < 2; ++sIt) {
        const int s = lane + sIt * 64;
        const float v = fine[s];
        int lo = 0, hi = 64;                 // count coarse <= v: answer space [0,64] -> 7 iters
        #pragma unroll
        for (int it = 0; it < 7; ++it) {
            if (lo < hi) {
                int mid = (lo + hi) >> 1;
                if (coarse[mid] <= v) lo = mid + 1; else hi = mid;
            }
        }
        s_z[wv][s + lo] = v;
    }
    __syncthreads();

    // ---- outputs: positions[N,192,3], viewdirs[N,192,3], z[N,192], deltas[N,192] ----
    // All stores nontemporal (ext_vector_type for the builtin): written once, never re-read.
    const float* zm = s_z[wv];
    f32x4* pos4 = reinterpret_cast<f32x4*>(out) + (size_t)r * 144;
    f32x4* vd4  = reinterpret_cast<f32x4*>(out + (size_t)NR * 576)  + (size_t)r * 144;
    f32x4* z4   = reinterpret_cast<f32x4*>(out + (size_t)NR * 1152) + (size_t)r * 48;
    f32x4* dl4  = reinterpret_cast<f32x4*>(out + (size_t)NR * 1344) + (size_t)r * 48;

    #pragma unroll
    for (int qi = 0; qi < 3; ++qi) {
        const int q = lane + qi * 64;
        if (q < 144) {
            const int f = 4 * q;
            f32x4 p, v;
            #pragma unroll
            for (int m = 0; m < 4; ++m) {
                const int k = (f + m) / 3;
                const int c = (f + m) % 3;
                const float zz = zm[k];
                const float dc = (c == 0) ? dx : ((c == 1) ? dy : dz);
                const float oc = (c == 0) ? ox : ((c == 1) ? oy : oz);
                p[m] = oc + zz * dc;
                v[m] = dc;
            }
            __builtin_nontemporal_store(p, pos4 + q);
            __builtin_nontemporal_store(v, vd4 + q);
        }
    }
    if (lane < 48) {
        const int f = 4 * lane;
        const float z0 = zm[f], z1 = zm[f+1], z2 = zm[f+2], z3 = zm[f+3];
        f32x4 zv; zv[0] = z0; zv[1] = z1; zv[2] = z2; zv[3] = z3;
        __builtin_nontemporal_store(zv, z4 + lane);
        const bool hasNext = (f + 4) < 192;
        const float e3 = hasNext ? (zm[f+4] - z3) : (z3 - z2);
        f32x4 dv; dv[0] = z1 - z0; dv[1] = z2 - z1; dv[2] = z3 - z2; dv[3] = e3;
        __builtin_nontemporal_store(dv, dl4 + lane);
    }
}

extern "C" void kernel_launch(void* const* d_in, const int* in_sizes, int n_in,
                              void* d_out, int out_size, void* d_ws, size_t ws_size,
                              hipStream_t stream) {
    const float* origins    = (const float*)d_in[0];
    const float* directions = (const float*)d_in[1];
    const float* nearv      = (const float*)d_in[2];
    const float* farv       = (const float*)d_in[3];
    const float* weights    = (const float*)d_in[4];
    float* out = (float*)d_out;

    dim3 grid(NR / RPB);
    dim3 block(256);
    ray_sampler_kernel<<<grid, block, 0, stream>>>(origins, directions, nearv, farv, weights, out);
}

// Round 5
// 81.558 us; speedup vs baseline: 1.0243x; 1.0148x over previous
//
#include <hip/hip_runtime.h>

#define NR 65536
#define RPB 4   // rays per 256-thread block (one wave per ray, waves fully independent)

typedef float f32x4 __attribute__((ext_vector_type(4)));

// Must be bit-identical at every use site (merge consistency): keep one helper.
__device__ __forceinline__ float coarse_at(int j, float nr, float dnf) {
    return fmaf((float)j * (1.0f / 63.0f), dnf, nr);
}

__global__ __launch_bounds__(256) void ray_sampler_kernel(
    const float* __restrict__ origins,
    const float* __restrict__ directions,
    const float* __restrict__ nearv,
    const float* __restrict__ farv,
    const float* __restrict__ weights,
    float* __restrict__ out)
{
    __shared__ float s_cdf[RPB][64];     // entries 0..62 used
    __shared__ float s_fine[RPB][128];
    __shared__ float s_z[RPB][192];
    __shared__ float s_pos[RPB][576];    // staged positions (192 x 3)
    __shared__ float s_vd[RPB][16];      // 12-float repeating viewdir pattern

    const int tid  = threadIdx.x;
    const int wv   = tid >> 6;
    const int lane = tid & 63;
    const int r    = blockIdx.x * RPB + wv;

    const float nr  = nearv[r];
    const float fr  = farv[r];
    const float dnf = fr - nr;

    float dx = directions[3*r+0];
    float dy = directions[3*r+1];
    float dz = directions[3*r+2];
    const float invn = 1.0f / sqrtf(dx*dx + dy*dy + dz*dz);
    dx *= invn; dy *= invn; dz *= invn;
    const float ox = origins[3*r+0];
    const float oy = origins[3*r+1];
    const float oz = origins[3*r+2];

    // viewdir pattern: s_vd[j] = d[(j%3)] for j<12; vd4 of output-q is row (q%3)
    if (lane < 12) {
        const int c = lane % 3;
        s_vd[wv][lane] = (c == 0) ? dx : ((c == 1) ? dy : dz);
    }

    // ---- CDF from 62 interior weights via wave prefix scan ----
    float w = 0.0f;
    if (lane < 62) w = weights[(size_t)r*64 + lane + 1] + 1e-5f;
    float sc = w;
    #pragma unroll
    for (int off = 1; off < 64; off <<= 1) {
        float t = __shfl_up(sc, off, 64);
        if (lane >= off) sc += t;
    }
    const float total = __shfl(sc, 63, 64);
    const float invT  = 1.0f / total;
    if (lane < 62) s_cdf[wv][lane + 1] = sc * invT;
    if (lane == 62) s_cdf[wv][0] = 0.0f;
    // No __syncthreads anywhere: each wave only touches its own LDS row;
    // same-wave DS ops are processed in order, compiler inserts lgkmcnt waits.

    // ---- 128 fine samples by inverse-CDF (searchsorted side='right') ----
    const float* cdf = s_cdf[wv];
    float fval0, fval1;
    #pragma unroll
    for (int sIt = 0; sIt < 2; ++sIt) {
        const int s = lane + sIt * 64;
        const float u = (float)s * (1.0f/127.0f);
        int lo = 0, hi = 63;                 // answer in [0,63]: 6 iters
        #pragma unroll
        for (int it = 0; it < 6; ++it) {
            if (lo < hi) {
                int mid = (lo + hi) >> 1;
                if (cdf[mid] <= u) lo = mid + 1; else hi = mid;
            }
        }
        int below = lo - 1; below = below < 0 ? 0 : (below > 62 ? 62 : below);
        int above = lo > 62 ? 62 : lo;
        const float cb = cdf[below], ca = cdf[above];
        // bins = midpoints: near + dnf*(j+0.5)/63
        const float bb = fmaf(((float)below + 0.5f) * (1.0f/63.0f), dnf, nr);
        const float ba = fmaf(((float)above + 0.5f) * (1.0f/63.0f), dnf, nr);
        float den = ca - cb;
        if (den < 1e-5f) den = 1.0f;
        const float tt = (u - cb) / den;
        const float fv = bb + tt * (ba - bb);
        s_fine[wv][s] = fv;
        if (sIt == 0) fval0 = fv; else fval1 = fv;
    }

    // ---- merge coarse(64, analytic) + fine(128, LDS) -> z(192) sorted ----
    const float* fine = s_fine[wv];
    {
        const float v = coarse_at(lane, nr, dnf);
        int lo = 0, hi = 128;                // count fine < v: 8 iters
        #pragma unroll
        for (int it = 0; it < 8; ++it) {
            if (lo < hi) {
                int mid = (lo + hi) >> 1;
                if (fine[mid] < v) lo = mid + 1; else hi = mid;
            }
        }
        s_z[wv][lane + lo] = v;
    }
    #pragma unroll
    for (int sIt = 0; sIt < 2; ++sIt) {
        const float v = (sIt == 0) ? fval0 : fval1;
        int lo = 0, hi = 64;                 // count coarse <= v: 7 iters, pure VALU
        #pragma unroll
        for (int it = 0; it < 7; ++it) {
            if (lo < hi) {
                int mid = (lo + hi) >> 1;
                if (coarse_at(mid, nr, dnf) <= v) lo = mid + 1; else hi = mid;
            }
        }
        s_z[wv][lane + sIt * 64 + lo] = v;
    }

    // ---- outputs ----
    const float* zm = s_z[wv];
    float* posb = out + (size_t)r * 576;
    float* vdb  = out + (size_t)NR * 576  + (size_t)r * 576;
    float* zb   = out + (size_t)NR * 1152 + (size_t)r * 192;
    float* dlb  = out + (size_t)NR * 1344 + (size_t)r * 192;

    // Pass 1: per-sample -> stage positions in LDS, stream z + deltas (contiguous b32)
    #pragma unroll
    for (int ri = 0; ri < 3; ++ri) {
        const int k  = lane + ri * 64;
        const float zz = zm[k];
        const int kn = (k == 191) ? 190 : (k + 1);
        const float zn = zm[kn];
        const float dl = fabsf(zn - zz);     // sorted z: works for the repeated last delta too
        s_pos[wv][3*k + 0] = fmaf(zz, dx, ox);
        s_pos[wv][3*k + 1] = fmaf(zz, dy, oy);
        s_pos[wv][3*k + 2] = fmaf(zz, dz, oz);
        __builtin_nontemporal_store(zz, zb + k);
        __builtin_nontemporal_store(dl, dlb + k);
    }

    // Pass 2: stream positions + viewdirs as full-line float4 NT stores
    int l3 = lane % 3;
    const f32x4* posp = reinterpret_cast<const f32x4*>(s_pos[wv]);
    const f32x4* vdp  = reinterpret_cast<const f32x4*>(s_vd[wv]);
    f32x4* pos4 = reinterpret_cast<f32x4*>(posb);
    f32x4* vd4  = reinterpret_cast<f32x4*>(vdb);
    #pragma unroll
    for (int qi = 0; qi < 2; ++qi) {
        const int q = lane + qi * 64;
        int p = l3 + qi; p -= (p >= 3) ? 3 : 0;   // (q % 3)
        __builtin_nontemporal_store(posp[q], pos4 + q);
        __builtin_nontemporal_store(vdp[p],  vd4 + q);
    }
    if (lane < 16) {
        const int q = 128 + lane;
        int p = l3 + 2; p -= (p >= 3) ? 3 : 0;
        __builtin_nontemporal_store(posp[q], pos4 + q);
        __builtin_nontemporal_store(vdp[p],  vd4 + q);
    }
}

extern "C" void kernel_launch(void* const* d_in, const int* in_sizes, int n_in,
                              void* d_out, int out_size, void* d_ws, size_t ws_size,
                              hipStream_t stream) {
    const float* origins    = (const float*)d_in[0];
    const float* directions = (const float*)d_in[1];
    const float* nearv      = (const float*)d_in[2];
    const float* farv       = (const float*)d_in[3];
    const float* weights    = (const float*)d_in[4];
    float* out = (float*)d_out;

    dim3 grid(NR / RPB);
    dim3 block(256);
    ray_sampler_kernel<<<grid, block, 0, stream>>>(origins, directions, nearv, farv, weights, out);
}